// Round 4
// baseline (305.498 us; speedup 1.0000x reference)
//
#include <hip/hip_runtime.h>

#define NP    128
#define NITER 100
#define BLK   256
#define RSC   72.13475204444817f    // log2(e)/EPS, EPS=0.02
#define IRSC  0.013862943611198906f // EPS*ln2 = 1/RSC

template<int CTRL>
__device__ __forceinline__ float dppf(float x) {
  return __int_as_float(__builtin_amdgcn_update_dpp(
      0, __float_as_int(x), CTRL, 0xf, 0xf, false));
}
// sum all-reduce across a 16-lane DPP row (rotations 1,2,4,8)
__device__ __forceinline__ float rowsum16(float x) {
  x += dppf<0x121>(x);  // row_ror:1
  x += dppf<0x122>(x);  // row_ror:2
  x += dppf<0x124>(x);  // row_ror:4
  x += dppf<0x128>(x);  // row_ror:8
  return x;
}
__device__ __forceinline__ float wsum64(float x) {
  #pragma unroll
  for (int s = 1; s < 64; s <<= 1) x += __shfl_xor(x, s);
  return x;
}

// Linear-domain Sinkhorn (algebraically identical to the log-domain reference):
//   K = 2^(-dist*RSC);  P[n] = a[n]/(K Q)[n];  Q[m] = b[m]/(K^T P)[m]
//   flow[n][m] = P[n]*Q[m]*K[n][m];  all quantities stay within fp32 range
//   (K >= 2^-102 since dist <= sqrt(2), weights >= 1e-30).
// Thread (i,j) of a 16x16 grid holds A = K[8i..][8j..] and B = K[8j..][8i..]
// in registers; both passes reduce over the 16 j-lanes via DPP rotations.
// launch_bounds(256,2): 128 tile VGPRs + working set must stay in arch VGPRs
// (256-cap). At (256,3) the allocator spilled the tiles -> 10.8 MB scratch
// writes/dispatch and ~3.5x dynamic instruction bloat (R3 counters).
__global__ __launch_bounds__(BLK, 2) void emd_sinkhorn(
    const float* __restrict__ j1g, const float* __restrict__ j2g,
    float* __restrict__ out)
{
  __shared__ __align__(16) float x1s[NP], y1s[NP], x2s[NP], y2s[NP];
  __shared__ __align__(16) float ah[NP + 4], bh[NP + 4];
  __shared__ __align__(16) float Pv[NP + 4], Qv[NP + 4];
  __shared__ float red[4];

  const int t  = threadIdx.x;
  const int l  = t & 63;
  const int wv = t >> 6;
  const int i  = t >> 4;   // row block 0..15
  const int j  = t & 15;   // col block 0..15 (= lane within DPP row)
  const int b  = blockIdx.x;
  const float* J1 = j1g + (size_t)b * (NP * 3);
  const float* J2 = j2g + (size_t)b * (NP * 3);

  // ---- load particles ----
  if (t < NP) {
    x1s[t] = J1[3*t]; y1s[t] = J1[3*t+1]; ah[t] = J1[3*t+2];
    x2s[t] = J2[3*t]; y2s[t] = J2[3*t+1]; bh[t] = J2[3*t+2];
  }
  __syncthreads();

  // ---- exact energies from raw weights (deterministic, redundant/wave) ----
  const float e1 = wsum64(ah[l] + ah[l + 64]);
  const float e2 = wsum64(bh[l] + bh[l + 64]);
  const float dE = fabsf(e2 - e1);
  __syncthreads();  // all reads of raw weights done before flooring in place

  if (t < NP) { ah[t] = fmaxf(ah[t], 1e-30f); bh[t] = fmaxf(bh[t], 1e-30f); }
  if (t == 0) {
    ah[NP] = fmaxf(fmaxf(e2 - e1, 0.0f), 1e-30f);
    bh[NP] = fmaxf(fmaxf(e1 - e2, 0.0f), 1e-30f);
  }
  if (t <= NP) Qv[t] = 1.0f;   // initial scaling vector (g = 0)

  // ---- build register tiles A (rows 8i, cols 8j) and B (rows 8j, cols 8i) ----
  float A[8][8], B[8][8];
  {
    float xcA[8], ycA[8], xcB[8], ycB[8];
    #pragma unroll
    for (int k = 0; k < 8; ++k) {
      xcA[k] = x2s[8*j + k]; ycA[k] = y2s[8*j + k];
      xcB[k] = x2s[8*i + k]; ycB[k] = y2s[8*i + k];
    }
    #pragma unroll
    for (int kr = 0; kr < 8; ++kr) {
      const float xrA = x1s[8*i + kr], yrA = y1s[8*i + kr];
      const float xrB = x1s[8*j + kr], yrB = y1s[8*j + kr];
      #pragma unroll
      for (int kc = 0; kc < 8; ++kc) {
        float dx = xcA[kc] - xrA + 1e-12f, dy = ycA[kc] - yrA + 1e-12f;
        A[kr][kc] = __builtin_amdgcn_exp2f(-__builtin_sqrtf(dx*dx + dy*dy) * RSC);
        dx = xcB[kc] - xrB + 1e-12f; dy = ycB[kc] - yrB + 1e-12f;
        B[kr][kc] = __builtin_amdgcn_exp2f(-__builtin_sqrtf(dx*dx + dy*dy) * RSC);
      }
    }
  }
  __syncthreads();

  const float4 a4a = *(const float4*)&ah[8*i];
  const float4 a4b = *(const float4*)&ah[8*i + 4];
  const float4 b4a = *(const float4*)&bh[8*i];
  const float4 b4b = *(const float4*)&bh[8*i + 4];
  const float aslk = ah[NP], bslk = bh[NP];

  for (int it = 0; it < NITER; ++it) {
    // ---------- row pass: P[n] = a[n] * rcp( sum_m K[n][m] Q[m] ) ----------
    {
      const float4 qa = *(const float4*)&Qv[8*j];
      const float4 qb = *(const float4*)&Qv[8*j + 4];
      const float q128 = Qv[NP];
      float r[8];
      #pragma unroll
      for (int kr = 0; kr < 8; ++kr)
        r[kr] = ((A[kr][0]*qa.x + A[kr][1]*qa.y) + (A[kr][2]*qa.z + A[kr][3]*qa.w))
              + ((A[kr][4]*qb.x + A[kr][5]*qb.y) + (A[kr][6]*qb.z + A[kr][7]*qb.w));
      float rs = ((qa.x + qa.y) + (qa.z + qa.w)) + ((qb.x + qb.y) + (qb.z + qb.w));
      #pragma unroll
      for (int kr = 0; kr < 8; ++kr) r[kr] = rowsum16(r[kr]);
      rs = rowsum16(rs);
      float p[8];
      p[0] = a4a.x * __builtin_amdgcn_rcpf(r[0] + q128);
      p[1] = a4a.y * __builtin_amdgcn_rcpf(r[1] + q128);
      p[2] = a4a.z * __builtin_amdgcn_rcpf(r[2] + q128);
      p[3] = a4a.w * __builtin_amdgcn_rcpf(r[3] + q128);
      p[4] = a4b.x * __builtin_amdgcn_rcpf(r[4] + q128);
      p[5] = a4b.y * __builtin_amdgcn_rcpf(r[5] + q128);
      p[6] = a4b.z * __builtin_amdgcn_rcpf(r[6] + q128);
      p[7] = a4b.w * __builtin_amdgcn_rcpf(r[7] + q128);
      if (j == 0) {
        *(float4*)&Pv[8*i]     = make_float4(p[0], p[1], p[2], p[3]);
        *(float4*)&Pv[8*i + 4] = make_float4(p[4], p[5], p[6], p[7]);
      }
      if (t == 0) Pv[NP] = aslk * __builtin_amdgcn_rcpf(rs + q128);
    }
    __syncthreads();
    // ---------- col pass: Q[m] = b[m] * rcp( sum_n K[n][m] P[n] ) ----------
    {
      const float4 pa = *(const float4*)&Pv[8*j];
      const float4 pb = *(const float4*)&Pv[8*j + 4];
      const float p128 = Pv[NP];
      float c[8];
      #pragma unroll
      for (int kc = 0; kc < 8; ++kc)
        c[kc] = ((B[0][kc]*pa.x + B[1][kc]*pa.y) + (B[2][kc]*pa.z + B[3][kc]*pa.w))
              + ((B[4][kc]*pb.x + B[5][kc]*pb.y) + (B[6][kc]*pb.z + B[7][kc]*pb.w));
      float cs = ((pa.x + pa.y) + (pa.z + pa.w)) + ((pb.x + pb.y) + (pb.z + pb.w));
      #pragma unroll
      for (int kc = 0; kc < 8; ++kc) c[kc] = rowsum16(c[kc]);
      cs = rowsum16(cs);
      float q[8];
      q[0] = b4a.x * __builtin_amdgcn_rcpf(c[0] + p128);
      q[1] = b4a.y * __builtin_amdgcn_rcpf(c[1] + p128);
      q[2] = b4a.z * __builtin_amdgcn_rcpf(c[2] + p128);
      q[3] = b4a.w * __builtin_amdgcn_rcpf(c[3] + p128);
      q[4] = b4b.x * __builtin_amdgcn_rcpf(c[4] + p128);
      q[5] = b4b.y * __builtin_amdgcn_rcpf(c[5] + p128);
      q[6] = b4b.z * __builtin_amdgcn_rcpf(c[6] + p128);
      q[7] = b4b.w * __builtin_amdgcn_rcpf(c[7] + p128);
      if (j == 0) {
        *(float4*)&Qv[8*i]     = make_float4(q[0], q[1], q[2], q[3]);
        *(float4*)&Qv[8*i + 4] = make_float4(q[4], q[5], q[6], q[7]);
      }
      if (t == 0) Qv[NP] = bslk * __builtin_amdgcn_rcpf(cs + p128);
    }
    __syncthreads();
  }

  // ---- emd = sum_{n,m<128} d * P[n]*Q[m]*K[n][m] + dE ;  d = -log2(K)/RSC ----
  float pr[8], qc[8];
  {
    const float4 pa = *(const float4*)&Pv[8*i];
    const float4 pb = *(const float4*)&Pv[8*i + 4];
    const float4 qa = *(const float4*)&Qv[8*j];
    const float4 qb = *(const float4*)&Qv[8*j + 4];
    pr[0]=pa.x; pr[1]=pa.y; pr[2]=pa.z; pr[3]=pa.w;
    pr[4]=pb.x; pr[5]=pb.y; pr[6]=pb.z; pr[7]=pb.w;
    qc[0]=qa.x; qc[1]=qa.y; qc[2]=qa.z; qc[3]=qa.w;
    qc[4]=qb.x; qc[5]=qb.y; qc[6]=qb.z; qc[7]=qb.w;
  }
  float acc = 0.0f;
  #pragma unroll
  for (int kr = 0; kr < 8; ++kr) {
    #pragma unroll
    for (int kc = 0; kc < 8; ++kc) {
      const float k = A[kr][kc];
      const float d = -__builtin_amdgcn_logf(k) * IRSC;
      acc = fmaf(d, (pr[kr] * k) * qc[kc], acc);
    }
  }
  acc = wsum64(acc);
  if (l == 0) red[wv] = acc;
  __syncthreads();
  if (t == 0) out[b] = ((red[0] + red[1]) + (red[2] + red[3])) + dE;
}

extern "C" void kernel_launch(void* const* d_in, const int* in_sizes, int n_in,
                              void* d_out, int out_size, void* d_ws, size_t ws_size,
                              hipStream_t stream) {
  const float* j1 = (const float*)d_in[0];
  const float* j2 = (const float*)d_in[1];
  float* outp = (float*)d_out;
  const int batch = in_sizes[0] / (NP * 3);
  hipLaunchKernelGGL(emd_sinkhorn, dim3(batch), dim3(BLK), 0, stream,
                     j1, j2, outp);
}